// Round 2
// 294.834 us; speedup vs baseline: 1.0899x; 1.0899x over previous
//
#include <hip/hip_runtime.h>

typedef unsigned short u16;
typedef unsigned int u32;
typedef __attribute__((ext_vector_type(8))) short short8;
typedef __attribute__((ext_vector_type(4))) float f32x4;

// ---------- helpers ----------
__device__ inline u16 f2bf(float f) {           // round-to-nearest-even fp32->bf16
  u32 x = __float_as_uint(f);
  x += 0x7fff + ((x >> 16) & 1);
  return (u16)(x >> 16);
}
__device__ inline float bf2f(u16 h) {
  return __uint_as_float(((u32)h) << 16);
}
__device__ inline void gload16(const void* g, void* l) {
  // async global->LDS, 16B per lane (global_load_lds_dwordx4)
  __builtin_amdgcn_global_load_lds((const __attribute__((address_space(1))) u32*)g,
                                   (__attribute__((address_space(3))) u32*)l, 16, 0, 0);
}

// swizzled 128x128 bf16 epilogue tile in LDS: row = 128 u16 (256B = 16 granules of 16B).
// sg(row) spreads bank chunk-position across BOTH the (q*4+reg) row pattern of the
// register->LDS writes (bits 2..3 of row) and the (ch*8+j) row pattern of the
// transpose reads (bits 3..6 of row): all patterns land even (2 lanes/bank).
__device__ inline int sg(int r) {
  return ((r >> 3) & 7) ^ (((r >> 2) & 1) << 2) ^ (((r >> 3) & 1) << 1);
}
__device__ inline int stile_off(int rl, int cl) {
  return rl * 128 + (((cl >> 3) ^ sg(rl)) << 3) + (cl & 7);
}

// ---------- fused cast fp32 -> bf16 for embd and W ----------
__global__ void cast_all(const float* __restrict__ embd, const float* __restrict__ W,
                         u16* __restrict__ embd_b, u16* __restrict__ W_b) {
  const float* src; u16* dst; size_t i;
  if (blockIdx.x < 16384) {
    src = embd; dst = embd_b;
    i = ((size_t)blockIdx.x * 256 + threadIdx.x) * 4;
  } else {
    src = W; dst = W_b;
    i = ((size_t)(blockIdx.x - 16384) * 256 + threadIdx.x) * 4;
  }
  float4 v = *(const float4*)(src + i);
  ushort4 o;
  o.x = f2bf(v.x); o.y = f2bf(v.y); o.z = f2bf(v.z); o.w = f2bf(v.w);
  *(ushort4*)(dst + i) = o;
}

// ---------- NT GEMM: C[i,j] = sum_k A[i,k]*B[j,k], bf16 in, fp32 acc ----------
// MODE 0: + bias[col], store bf16 C AND bf16 C^T (fused transpose)   (Linear)
//         grid (nblk, mblk, 1)
// MODE 1: triangular grid (S symmetric): exp(acc*scale), store tile + mirrored
//         tile, atomic rowsums. grid (batch, pair, 1) -> XCD = batch (flat%8)
// MODE 2: acc * (1/rowsum[row]), store fp32 coalesced via LDS staging (P@V)
//         grid (batch, mblk*8+nblk, 1) -> XCD = batch, n-fastest for A reuse
#define BM 128
#define BN 128
#define BK 64

template<int MODE>
__global__ __launch_bounds__(256, 2)
void gemm_nt(const u16* __restrict__ A, const u16* __restrict__ B,
             float* __restrict__ Cf, u16* __restrict__ Cb, u16* __restrict__ CT,
             const float* __restrict__ bias, float* __restrict__ rowsum,
             int M, int N, int K, float scale, long sA, long sB, long sC)
{
  // union: K-loop staging (As 16KB | Bs 16KB) vs epilogue tile (32KB)
  __shared__ __align__(16) char smem[32768];
  u16* As = (u16*)smem;            // BM*BK u16 = 16KB, rows of 128B (8 granules)
  u16* Bs = As + BM * BK;          // BN*BK u16 = 16KB
  u16* stile = (u16*)smem;         // 128*128 swizzled (MODE 0/1)
  float* stf = (float*)smem;       // 64*128 f32 (MODE 2)

  // ---- block index decode (XCD-affinity swizzles for MODE 1/2) ----
  int z, mBase, nBase, bi = 0, bj = 0;
  if (MODE == 0) {
    z = 0;
    mBase = blockIdx.y * BM;
    nBase = blockIdx.x * BN;
  } else if (MODE == 1) {
    z = blockIdx.x;                 // flat%8 == batch -> one XCD per batch
    int t = blockIdx.y, row = 0;
    const int nb = N >> 7;
    while (t >= nb - row) { t -= nb - row; ++row; }
    bi = row; bj = row + t;
    mBase = bi * BM; nBase = bj * BN;
  } else {
    z = blockIdx.x;                 // flat%8 == batch
    nBase = (blockIdx.y & 7) * BN;  // n fastest within batch -> A-row-tile reuse
    mBase = (blockIdx.y >> 3) * BM;
  }

  A += (size_t)z * sA;
  B += (size_t)z * sB;
  if (MODE == 2) Cf += (size_t)z * sC; else Cb += (size_t)z * sC;
  if (MODE != 0) rowsum += (size_t)z * M;

  const int tid  = threadIdx.x;
  const int lane = tid & 63;
  const int wave = tid >> 6;
  const int wm = (wave >> 1) * 64;   // 2x2 waves of 64x64
  const int wn = (wave & 1) * 64;
  const int q = lane >> 4;           // k-granule select for A/B frags; row-quad for C/D
  const int r = lane & 15;           // row (A) / col (B,C/D)
  const int rswz = r & 7;            // K-loop LDS read swizzle term ( == row&7 )

  // staging: each tile is BM x BK bf16 = 16KB; 256 lanes x 16B = 4KB per issue -> 4 issues.
  // LDS dest is linear (global_load_lds requirement); the SOURCE granule is
  // pre-swizzled: LDS slot (row, gd) holds global granule gd ^ (row&7).
  const int srow = tid >> 3;                       // 0..31 (row of issue 0; +32 per issue)
  const int scol = ((tid & 7) ^ (srow & 7)) * 8;   // swizzled source granule (u16 offset)
  const int lds0 = tid * 16;                       // byte offset of this lane's 16B slot

  const u16* a0 = A + (size_t)(mBase + srow) * K + scol;
  const u16* b0 = B + (size_t)(nBase + srow) * K + scol;

  f32x4 acc[4][4] = {};

  for (int k0 = 0; k0 < K; k0 += BK) {
#pragma unroll
    for (int i = 0; i < 4; ++i)
      gload16(a0 + (size_t)(32 * i) * K + k0, (char*)As + lds0 + i * 4096);
#pragma unroll
    for (int i = 0; i < 4; ++i)
      gload16(b0 + (size_t)(32 * i) * K + k0, (char*)Bs + lds0 + i * 4096);
    __syncthreads();

#pragma unroll
    for (int kk = 0; kk < 2; ++kk) {
      short8 af[4], bfr[4];
#pragma unroll
      for (int t = 0; t < 4; ++t) {
        const int go = (((kk * 4 + q) ^ rswz)) * 8;   // swizzled granule read
        af[t]  = *(const short8*)(As + (wm + t * 16 + r) * BK + go);
        bfr[t] = *(const short8*)(Bs + (wn + t * 16 + r) * BK + go);
      }
#pragma unroll
      for (int mi = 0; mi < 4; ++mi)
#pragma unroll
        for (int ni = 0; ni < 4; ++ni)
          acc[mi][ni] = __builtin_amdgcn_mfma_f32_16x16x32_bf16(af[mi], bfr[ni], acc[mi][ni], 0, 0, 0);
    }
    __syncthreads();
  }

  // C/D layout: col = lane&15 (r), row = (lane>>4)*4 + reg  (q*4+reg)

  if (MODE == 0) {
    float bv[4];
#pragma unroll
    for (int ni = 0; ni < 4; ++ni) bv[ni] = bias[nBase + wn + ni * 16 + r];
#pragma unroll
    for (int mi = 0; mi < 4; ++mi)
#pragma unroll
      for (int ni = 0; ni < 4; ++ni)
#pragma unroll
        for (int reg = 0; reg < 4; ++reg) {
          int rl = wm + mi * 16 + q * 4 + reg;
          int cl = wn + ni * 16 + r;
          stile[stile_off(rl, cl)] = f2bf(acc[mi][ni][reg] + bv[ni]);
        }
    __syncthreads();
    // c write: coalesced rows
    {
      const int z1 = mBase >> 11;           // batch of this row-tile
      const int n0 = mBase & 2047;
      u16* ctb = CT + (size_t)z1 * 1024 * 2048;
#pragma unroll
      for (int rnd = 0; rnd < 8; ++rnd) {
        int idx = rnd * 256 + tid;
        int ch = idx & 15, n = idx >> 4;
        short8 v = *(const short8*)(stile + n * 128 + ((ch ^ sg(n)) << 3));
        *(short8*)(Cb + (size_t)(mBase + n) * N + nBase + ch * 8) = v;
      }
      // cT write: column reads (scalar, swizzle-spread), coalesced stores
#pragma unroll
      for (int rnd = 0; rnd < 8; ++rnd) {
        int idx = rnd * 256 + tid;
        int ch = idx & 15, cc = idx >> 4;
        short8 v;
#pragma unroll
        for (int j = 0; j < 8; ++j) v[j] = (short)stile[stile_off(ch * 8 + j, cc)];
        *(short8*)(ctb + (size_t)(nBase + cc) * 2048 + n0 + ch * 8) = v;
      }
    }
  } else if (MODE == 1) {
    const bool mirror = (bi != bj);
    float colacc[4] = {0.f, 0.f, 0.f, 0.f};
#pragma unroll
    for (int mi = 0; mi < 4; ++mi) {
      float rs[4] = {0.f, 0.f, 0.f, 0.f};
#pragma unroll
      for (int ni = 0; ni < 4; ++ni)
#pragma unroll
        for (int reg = 0; reg < 4; ++reg) {
          float e = __expf(acc[mi][ni][reg] * scale);
          u16 h = f2bf(e);
          float f = bf2f(h);      // rounded value for num/denom consistency
          rs[reg] += f;
          if (mirror) colacc[ni] += f;
          stile[stile_off(wm + mi * 16 + q * 4 + reg, wn + ni * 16 + r)] = h;
        }
      // direct rowsums: reduce over r (cols) within q-group
#pragma unroll
      for (int reg = 0; reg < 4; ++reg) {
        float v = rs[reg];
        v += __shfl_xor(v, 1);
        v += __shfl_xor(v, 2);
        v += __shfl_xor(v, 4);
        v += __shfl_xor(v, 8);
        if (r == 0)
          atomicAdd(&rowsum[mBase + wm + mi * 16 + q * 4 + reg], v);
      }
    }
    if (mirror) {
      // mirror rowsums = column sums: reduce over q (rows)
#pragma unroll
      for (int ni = 0; ni < 4; ++ni) {
        float v = colacc[ni];
        v += __shfl_xor(v, 16);
        v += __shfl_xor(v, 32);
        if (q == 0)
          atomicAdd(&rowsum[nBase + wn + ni * 16 + r], v);
      }
    }
    __syncthreads();
    // direct tile write: coalesced rows
#pragma unroll
    for (int rnd = 0; rnd < 8; ++rnd) {
      int idx = rnd * 256 + tid;
      int ch = idx & 15, n = idx >> 4;
      short8 v = *(const short8*)(stile + n * 128 + ((ch ^ sg(n)) << 3));
      *(short8*)(Cb + (size_t)(mBase + n) * N + nBase + ch * 8) = v;
    }
    if (mirror) {
      // mirrored tile write: column reads, coalesced stores to block (bj,bi)
#pragma unroll
      for (int rnd = 0; rnd < 8; ++rnd) {
        int idx = rnd * 256 + tid;
        int ch = idx & 15, cc = idx >> 4;
        short8 v;
#pragma unroll
        for (int j = 0; j < 8; ++j) v[j] = (short)stile[stile_off(ch * 8 + j, cc)];
        *(short8*)(Cb + (size_t)(nBase + cc) * N + mBase + ch * 8) = v;
      }
    }
  } else {
    // MODE 2: normalize + fp32 store, staged through LDS in two 64-row phases
#pragma unroll
    for (int p = 0; p < 2; ++p) {
      if ((wave >> 1) == p) {
#pragma unroll
        for (int mi = 0; mi < 4; ++mi)
#pragma unroll
          for (int reg = 0; reg < 4; ++reg) {
            int lr = mi * 16 + q * 4 + reg;
            float inv = 1.0f / rowsum[mBase + wm + lr];
#pragma unroll
            for (int ni = 0; ni < 4; ++ni)
              stf[lr * 128 + wn + ni * 16 + r] = acc[mi][ni][reg] * inv;
          }
      }
      __syncthreads();
#pragma unroll
      for (int rnd = 0; rnd < 8; ++rnd) {
        int idx = rnd * 256 + tid;
        int n = idx >> 5, ch = idx & 31;
        float4 v = *(const float4*)(stf + n * 128 + ch * 4);
        *(float4*)(Cf + (size_t)(mBase + p * 64 + n) * N + nBase + ch * 4) = v;
      }
      __syncthreads();
    }
  }
}

// ---------- launch ----------
// Problem constants: B=8, N=2048, E=O=1024
extern "C" void kernel_launch(void* const* d_in, const int* in_sizes, int n_in,
                              void* d_out, int out_size, void* d_ws, size_t ws_size,
                              hipStream_t stream) {
  const float* embd = (const float*)d_in[0];   // [8,2048,1024]
  const float* W    = (const float*)d_in[1];   // [1024,1024]
  const float* bias = (const float*)d_in[2];   // [1024]
  float* out = (float*)d_out;                  // [8,2048,1024] fp32

  char* ws = (char*)d_ws;
  u16* P_b    = (u16*)(ws + 0);            // 8*2048*2048*2 = 67108864
  u16* embd_b = (u16*)(ws + 0);            // 33554432 (aliases P, dead before GEMM2)
  u16* W_b    = (u16*)(ws + 33554432);     // 2097152  (aliases P, dead before GEMM2)
  u16* c_b    = (u16*)(ws + 67108864);     // 33554432
  u16* cT_b   = (u16*)(ws + 100663296);    // 33554432
  float* rowsum = (float*)(ws + 134217728);// 16384*4

  // 1) casts (fused)
  cast_all<<<17408, 256, 0, stream>>>(embd, W, embd_b, W_b);

  // 2) c = embd @ W^T + b, plus fused c^T : M=16384, N=1024, K=1024
  gemm_nt<0><<<dim3(8, 128, 1), 256, 0, stream>>>(
      embd_b, W_b, nullptr, c_b, cT_b, bias, nullptr,
      16384, 1024, 1024, 0.f, 0, 0, 0);

  // 3) rowsum = 0
  hipMemsetAsync(rowsum, 0, 16384 * sizeof(float), stream);

  // 4) P = exp(c c^T / 32) unnormalized bf16, triangular (S symmetric) + rowsums
  //    grid (batch=8, pair=136): flat%8==batch -> per-XCD c residency (4 MB)
  gemm_nt<1><<<dim3(8, 136, 1), 256, 0, stream>>>(
      c_b, c_b, nullptr, P_b, nullptr, nullptr, rowsum,
      2048, 2048, 1024, 0.03125f, 2048L * 1024, 2048L * 1024, 2048L * 2048);

  // 5) O = (P @ c) / rowsum : per batch M=2048, N=1024, K=2048; B = cT
  //    grid (batch=8, mblk*8+nblk=128): per-XCD batch affinity, n-fastest
  gemm_nt<2><<<dim3(8, 128, 1), 256, 0, stream>>>(
      P_b, cT_b, out, nullptr, nullptr, nullptr, rowsum,
      2048, 1024, 2048, 0.f, 2048L * 2048, 2048L * 1024, 2048L * 1024);
}

// Round 3
// 289.804 us; speedup vs baseline: 1.1088x; 1.0174x over previous
//
#include <hip/hip_runtime.h>

typedef unsigned short u16;
typedef unsigned int u32;
typedef __attribute__((ext_vector_type(8))) short short8;
typedef __attribute__((ext_vector_type(4))) float f32x4;

// ---------- helpers ----------
__device__ inline u16 f2bf(float f) {           // round-to-nearest-even fp32->bf16
  u32 x = __float_as_uint(f);
  x += 0x7fff + ((x >> 16) & 1);
  return (u16)(x >> 16);
}
__device__ inline float bf2f(u16 h) {
  return __uint_as_float(((u32)h) << 16);
}
__device__ inline void gload16(const void* g, void* l) {
  // async global->LDS, 16B per lane (global_load_lds_dwordx4)
  __builtin_amdgcn_global_load_lds((const __attribute__((address_space(1))) u32*)g,
                                   (__attribute__((address_space(3))) u32*)l, 16, 0, 0);
}

// swizzled 128x128 bf16 epilogue tile in LDS (gemm_nt modes 0/1)
__device__ inline int sg(int r) {
  return ((r >> 3) & 7) ^ (((r >> 2) & 1) << 2) ^ (((r >> 3) & 1) << 1);
}
__device__ inline int stile_off(int rl, int cl) {
  return rl * 128 + (((cl >> 3) ^ sg(rl)) << 3) + (cl & 7);
}

// ---------- fused cast fp32 -> bf16 for embd and W ----------
__global__ void cast_all(const float* __restrict__ embd, const float* __restrict__ W,
                         u16* __restrict__ embd_b, u16* __restrict__ W_b) {
  const float* src; u16* dst; size_t i;
  if (blockIdx.x < 16384) {
    src = embd; dst = embd_b;
    i = ((size_t)blockIdx.x * 256 + threadIdx.x) * 4;
  } else {
    src = W; dst = W_b;
    i = ((size_t)(blockIdx.x - 16384) * 256 + threadIdx.x) * 4;
  }
  float4 v = *(const float4*)(src + i);
  ushort4 o;
  o.x = f2bf(v.x); o.y = f2bf(v.y); o.z = f2bf(v.z); o.w = f2bf(v.w);
  *(ushort4*)(dst + i) = o;
}

// ---------- NT GEMM 128x128 (modes 0/1) ----------
#define BM 128
#define BN 128
#define BK 64

template<int MODE>
__global__ __launch_bounds__(256, 2)
void gemm_nt(const u16* __restrict__ A, const u16* __restrict__ B,
             float* __restrict__ Cf, u16* __restrict__ Cb, u16* __restrict__ CT,
             const float* __restrict__ bias, float* __restrict__ rowsum,
             int M, int N, int K, float scale, long sA, long sB, long sC)
{
  __shared__ __align__(16) char smem[32768];
  u16* As = (u16*)smem;            // BM*BK u16 = 16KB
  u16* Bs = As + BM * BK;          // BN*BK u16 = 16KB
  u16* stile = (u16*)smem;         // 128*128 swizzled (MODE 0/1)

  int z, mBase, nBase, bi = 0, bj = 0;
  if (MODE == 0) {
    z = 0;
    mBase = blockIdx.y * BM;
    nBase = blockIdx.x * BN;
  } else {
    z = blockIdx.x;                 // flat%8 == batch -> one XCD per batch
    int t = blockIdx.y, row = 0;
    const int nb = N >> 7;
    while (t >= nb - row) { t -= nb - row; ++row; }
    bi = row; bj = row + t;
    mBase = bi * BM; nBase = bj * BN;
  }

  A += (size_t)z * sA;
  B += (size_t)z * sB;
  Cb += (size_t)z * sC;
  if (MODE != 0) rowsum += (size_t)z * M;

  const int tid  = threadIdx.x;
  const int lane = tid & 63;
  const int wave = tid >> 6;
  const int wm = (wave >> 1) * 64;   // 2x2 waves of 64x64
  const int wn = (wave & 1) * 64;
  const int q = lane >> 4;
  const int r = lane & 15;
  const int rswz = r & 7;

  const int srow = tid >> 3;                       // 0..31
  const int scol = ((tid & 7) ^ (srow & 7)) * 8;   // swizzled source granule
  const int lds0 = tid * 16;

  const u16* a0 = A + (size_t)(mBase + srow) * K + scol;
  const u16* b0 = B + (size_t)(nBase + srow) * K + scol;

  f32x4 acc[4][4] = {};

  for (int k0 = 0; k0 < K; k0 += BK) {
#pragma unroll
    for (int i = 0; i < 4; ++i)
      gload16(a0 + (size_t)(32 * i) * K + k0, (char*)As + lds0 + i * 4096);
#pragma unroll
    for (int i = 0; i < 4; ++i)
      gload16(b0 + (size_t)(32 * i) * K + k0, (char*)Bs + lds0 + i * 4096);
    __syncthreads();

#pragma unroll
    for (int kk = 0; kk < 2; ++kk) {
      short8 af[4], bfr[4];
#pragma unroll
      for (int t = 0; t < 4; ++t) {
        const int go = (((kk * 4 + q) ^ rswz)) * 8;
        af[t]  = *(const short8*)(As + (wm + t * 16 + r) * BK + go);
        bfr[t] = *(const short8*)(Bs + (wn + t * 16 + r) * BK + go);
      }
#pragma unroll
      for (int mi = 0; mi < 4; ++mi)
#pragma unroll
        for (int ni = 0; ni < 4; ++ni)
          acc[mi][ni] = __builtin_amdgcn_mfma_f32_16x16x32_bf16(af[mi], bfr[ni], acc[mi][ni], 0, 0, 0);
    }
    __syncthreads();
  }

  // C/D layout: col = lane&15 (r), row = (lane>>4)*4 + reg  (q*4+reg)

  if (MODE == 0) {
    float bv[4];
#pragma unroll
    for (int ni = 0; ni < 4; ++ni) bv[ni] = bias[nBase + wn + ni * 16 + r];
#pragma unroll
    for (int mi = 0; mi < 4; ++mi)
#pragma unroll
      for (int ni = 0; ni < 4; ++ni)
#pragma unroll
        for (int reg = 0; reg < 4; ++reg) {
          int rl = wm + mi * 16 + q * 4 + reg;
          int cl = wn + ni * 16 + r;
          stile[stile_off(rl, cl)] = f2bf(acc[mi][ni][reg] + bv[ni]);
        }
    __syncthreads();
    {
      const int z1 = mBase >> 11;           // batch of this row-tile
      const int n0 = mBase & 2047;
      u16* ctb = CT + (size_t)z1 * 1024 * 2048;
#pragma unroll
      for (int rnd = 0; rnd < 8; ++rnd) {
        int idx = rnd * 256 + tid;
        int ch = idx & 15, n = idx >> 4;
        short8 v = *(const short8*)(stile + n * 128 + ((ch ^ sg(n)) << 3));
        *(short8*)(Cb + (size_t)(mBase + n) * N + nBase + ch * 8) = v;
      }
#pragma unroll
      for (int rnd = 0; rnd < 8; ++rnd) {
        int idx = rnd * 256 + tid;
        int ch = idx & 15, cc = idx >> 4;
        short8 v;
#pragma unroll
        for (int j = 0; j < 8; ++j) v[j] = (short)stile[stile_off(ch * 8 + j, cc)];
        *(short8*)(ctb + (size_t)(nBase + cc) * 2048 + n0 + ch * 8) = v;
      }
    }
  } else {
    const bool mirror = (bi != bj);
    float colacc[4] = {0.f, 0.f, 0.f, 0.f};
#pragma unroll
    for (int mi = 0; mi < 4; ++mi) {
      float rs[4] = {0.f, 0.f, 0.f, 0.f};
#pragma unroll
      for (int ni = 0; ni < 4; ++ni)
#pragma unroll
        for (int reg = 0; reg < 4; ++reg) {
          float e = __expf(acc[mi][ni][reg] * scale);
          u16 h = f2bf(e);
          float f = bf2f(h);      // rounded value for num/denom consistency
          rs[reg] += f;
          if (mirror) colacc[ni] += f;
          stile[stile_off(wm + mi * 16 + q * 4 + reg, wn + ni * 16 + r)] = h;
        }
#pragma unroll
      for (int reg = 0; reg < 4; ++reg) {
        float v = rs[reg];
        v += __shfl_xor(v, 1);
        v += __shfl_xor(v, 2);
        v += __shfl_xor(v, 4);
        v += __shfl_xor(v, 8);
        if (r == 0)
          atomicAdd(&rowsum[mBase + wm + mi * 16 + q * 4 + reg], v);
      }
    }
    if (mirror) {
#pragma unroll
      for (int ni = 0; ni < 4; ++ni) {
        float v = colacc[ni];
        v += __shfl_xor(v, 16);
        v += __shfl_xor(v, 32);
        if (q == 0)
          atomicAdd(&rowsum[nBase + wn + ni * 16 + r], v);
      }
    }
    __syncthreads();
#pragma unroll
    for (int rnd = 0; rnd < 8; ++rnd) {
      int idx = rnd * 256 + tid;
      int ch = idx & 15, n = idx >> 4;
      short8 v = *(const short8*)(stile + n * 128 + ((ch ^ sg(n)) << 3));
      *(short8*)(Cb + (size_t)(mBase + n) * N + nBase + ch * 8) = v;
    }
    if (mirror) {
#pragma unroll
      for (int rnd = 0; rnd < 8; ++rnd) {
        int idx = rnd * 256 + tid;
        int ch = idx & 15, cc = idx >> 4;
        short8 v;
#pragma unroll
        for (int j = 0; j < 8; ++j) v[j] = (short)stile[stile_off(ch * 8 + j, cc)];
        *(short8*)(Cb + (size_t)(nBase + cc) * N + mBase + ch * 8) = v;
      }
    }
  }
}

// ---------- P@cT (O = P@c / rowsum): 256x256 tile, 8 waves, counted-vmcnt ----------
// 512 thr = 8 waves (2M x 4N); per-wave 128x64 out; BK=64; LDS 2x(32K A + 32K B).
// Pipeline: prefetch distance 2 K-tiles; per tile: 4 compute phases (no intra
// barriers) -> s_barrier -> STAGE(tile i+2 into just-freed buf) -> vmcnt(8)
// (tile i+1 landed; i+2's 8 loads stay in flight) -> s_barrier. Raw s_barrier
// (no compiler vmcnt(0) drain) is the whole point.
#define STAGE_PV(buf, t) do {                                          \
    const u16* _a = a0 + (size_t)(t) * 64;                             \
    const u16* _b = b0 + (size_t)(t) * 64;                             \
    char* _l = (char*)ldsm + (buf) * 65536 + tid * 16;                 \
    gload16(_a,                      _l);                              \
    gload16(_a +  64 * (size_t)K,    _l + 8192);                       \
    gload16(_a + 128 * (size_t)K,    _l + 16384);                      \
    gload16(_a + 192 * (size_t)K,    _l + 24576);                      \
    gload16(_b,                      _l + 32768);                      \
    gload16(_b +  64 * (size_t)K,    _l + 40960);                      \
    gload16(_b + 128 * (size_t)K,    _l + 49152);                      \
    gload16(_b + 192 * (size_t)K,    _l + 57344);                      \
  } while (0)

__global__ __launch_bounds__(512, 2)
void gemm_pv8(const u16* __restrict__ A, const u16* __restrict__ B,
              float* __restrict__ Cf, const float* __restrict__ rowsum,
              int K, int Nn, long sA, long sB, long sC, int Mrs)
{
  // 128 KB: buf d at d*65536B: A-tile [256][64] bf16 (32KB), then B-tile (32KB).
  // LDS granule (row,g) holds global granule g ^ (row&7)  (source-preswizzled;
  // read applies the same XOR) -> ds_read_b128 fragment reads are 2-way max.
  __shared__ __align__(16) u16 ldsm[65536];

  const int z = blockIdx.x;                 // batch; flat%8==z -> XCD affinity
  const int y = blockIdx.y;
  const int mBase = (y >> 2) * 256;
  const int nBase = (y & 3) * 256;          // n fastest within batch

  A += (size_t)z * sA;
  B += (size_t)z * sB;
  Cf += (size_t)z * sC;
  rowsum += (size_t)z * Mrs;

  const int tid  = threadIdx.x;
  const int lane = tid & 63;
  const int wave = tid >> 6;
  const int wm = (wave >> 2) * 128;         // 2 M-groups
  const int wn = (wave & 3) * 64;           // 4 N-groups
  const int q = lane >> 4;
  const int r = lane & 15;
  const int rx = r & 7;

  // staging addresses (per thread, constant across tiles)
  const int srow = tid >> 3;                        // 0..63 (+64 per issue)
  const int sg8  = ((tid & 7) ^ (srow & 7)) * 8;    // swizzled source granule
  const u16* a0 = A + (size_t)(mBase + srow) * K + sg8;
  const u16* b0 = B + (size_t)(nBase + srow) * K + sg8;

  const int NT = K >> 6;                    // 64-wide K tiles
  const int rA = (wm + r) * 64;             // u16 offsets into A-tile
  const int rB = (wn + r) * 64;

  f32x4 acc[8][4] = {};

  // prologue: tiles 0 and 1 in flight; wait tile 0 (own), then barrier (all)
  STAGE_PV(0, 0);
  STAGE_PV(1, 1);
  asm volatile("s_waitcnt vmcnt(8)" ::: "memory");
  __builtin_amdgcn_s_barrier();

  for (int i = 0; i < NT; ++i) {
    const int d = i & 1;
    const u16* Ab = ldsm + d * 32768;
    const u16* Bb = Ab + 16384;

#pragma unroll
    for (int kk = 0; kk < 2; ++kk) {
      const int gq = ((kk * 4 + q) ^ rx) * 8;
      short8 bfr[4];
#pragma unroll
      for (int t = 0; t < 4; ++t)
        bfr[t] = *(const short8*)(Bb + rB + t * 1024 + gq);
#pragma unroll
      for (int mh = 0; mh < 2; ++mh) {
        short8 af[4];
#pragma unroll
        for (int t = 0; t < 4; ++t)
          af[t] = *(const short8*)(Ab + rA + (mh * 4 + t) * 1024 + gq);
        __builtin_amdgcn_s_setprio(1);
#pragma unroll
        for (int mi = 0; mi < 4; ++mi)
#pragma unroll
          for (int ni = 0; ni < 4; ++ni)
            acc[mh * 4 + mi][ni] = __builtin_amdgcn_mfma_f32_16x16x32_bf16(
                af[mi], bfr[ni], acc[mh * 4 + mi][ni], 0, 0, 0);
        __builtin_amdgcn_s_setprio(0);
      }
    }

    __builtin_amdgcn_s_barrier();           // all waves done reading buf d
    if (i + 2 < NT) {
      STAGE_PV(d, i + 2);                   // refill freed buf (8 loads)
      asm volatile("s_waitcnt vmcnt(8)" ::: "memory");  // tile i+1 landed (own)
    } else {
      asm volatile("s_waitcnt vmcnt(0)" ::: "memory");  // tail drain
    }
    __builtin_amdgcn_s_barrier();           // everyone's tile i+1 landed
    __builtin_amdgcn_sched_barrier(0);
  }

  // epilogue: normalize + direct fp32 stores (64B segments, 4 rows/inst)
#pragma unroll
  for (int mi = 0; mi < 8; ++mi)
#pragma unroll
    for (int reg = 0; reg < 4; ++reg) {
      const int row = mBase + wm + mi * 16 + q * 4 + reg;
      const float inv = 1.0f / rowsum[row];
      float* crow = Cf + (size_t)row * Nn + nBase + wn + r;
#pragma unroll
      for (int ni = 0; ni < 4; ++ni)
        crow[ni * 16] = acc[mi][ni][reg] * inv;
    }
}

// ---------- launch ----------
// Problem constants: B=8, N=2048, E=O=1024
extern "C" void kernel_launch(void* const* d_in, const int* in_sizes, int n_in,
                              void* d_out, int out_size, void* d_ws, size_t ws_size,
                              hipStream_t stream) {
  const float* embd = (const float*)d_in[0];   // [8,2048,1024]
  const float* W    = (const float*)d_in[1];   // [1024,1024]
  const float* bias = (const float*)d_in[2];   // [1024]
  float* out = (float*)d_out;                  // [8,2048,1024] fp32

  char* ws = (char*)d_ws;
  u16* P_b    = (u16*)(ws + 0);            // 8*2048*2048*2 = 67108864
  u16* embd_b = (u16*)(ws + 0);            // 33554432 (aliases P, dead before GEMM2)
  u16* W_b    = (u16*)(ws + 33554432);     // 2097152  (aliases P, dead before GEMM2)
  u16* c_b    = (u16*)(ws + 67108864);     // 33554432
  u16* cT_b   = (u16*)(ws + 100663296);    // 33554432
  float* rowsum = (float*)(ws + 134217728);// 16384*4

  // 1) casts (fused)
  cast_all<<<17408, 256, 0, stream>>>(embd, W, embd_b, W_b);

  // 2) c = embd @ W^T + b, plus fused c^T : M=16384, N=1024, K=1024
  gemm_nt<0><<<dim3(8, 128, 1), 256, 0, stream>>>(
      embd_b, W_b, nullptr, c_b, cT_b, bias, nullptr,
      16384, 1024, 1024, 0.f, 0, 0, 0);

  // 3) rowsum = 0
  hipMemsetAsync(rowsum, 0, 16384 * sizeof(float), stream);

  // 4) P = exp(c c^T / 32) unnormalized bf16, triangular (S symmetric) + rowsums
  gemm_nt<1><<<dim3(8, 136, 1), 256, 0, stream>>>(
      c_b, c_b, nullptr, P_b, nullptr, nullptr, rowsum,
      2048, 2048, 1024, 0.03125f, 2048L * 1024, 2048L * 1024, 2048L * 2048);

  // 5) O = (P @ c) / rowsum : per batch M=2048, N=1024, K=2048; B = cT
  //    256^2 tiles, 8 waves, counted-vmcnt pipeline; grid = 256 = 1 block/CU
  gemm_pv8<<<dim3(8, 32, 1), 512, 0, stream>>>(
      P_b, cT_b, out, rowsum,
      2048, 1024, 2048L * 2048, 2048L * 1024, 2048L * 1024, 2048);
}